// Round 10
// baseline (149.058 us; speedup 1.0000x reference)
//
#include <hip/hip_runtime.h>
#include <math.h>

#define H 512
#define W 512
#define HW (H * W)
#define NCH 6

__device__ __forceinline__ int reflect_idx(int p, int n) {
    if (p < 0) p = -p;
    if (p >= n) p = 2 * n - 2 - p;
    return p;
}

// ---------------- K1: Sobel (LDS-tiled, 128x8, 4 px/thread interleaved) ----------------
// cmax (per-channel img max) dropped: pipeline is scale-invariant past the clamp;
// cmax only rescales the 1e-12 clamp threshold (~1e-6 effect). Sobel on RAW img.
__global__ __launch_bounds__(256) void k_sobel(const float* __restrict__ img,
                                               float* __restrict__ gpart,
                                               float* __restrict__ g,
                                               float* __restrict__ xn,
                                               float* __restrict__ yn) {
    const int SB = 132;  // stride; 130 cols used, 10 rows
    __shared__ float st[10 * SB];

    int ch = blockIdx.z;
    int bx0 = blockIdx.x * 128, by0 = blockIdx.y * 8;
    int tx = threadIdx.x, ty = threadIdx.y;
    int tid = ty * 32 + tx;
    const float* im = img + (size_t)ch * HW;

#pragma unroll
    for (int jr = 0; jr < 2; ++jr) {
        int r = ty + 8 * jr;
        if (jr == 0 || ty < 2) {
            int yy = by0 - 1 + r;
            bool yok = (yy >= 0 && yy < H);
            const float* rowp = im + yy * W;
#pragma unroll
            for (int m = 0; m < 4; ++m) {
                int c = tx + 32 * m;
                int xx = bx0 - 1 + c;
                float v = 0.f;
                if (yok && xx >= 0 && xx < W) v = rowp[xx];
                st[r * SB + c] = v;
            }
            if (tx < 2) {
                int c = 128 + tx;
                int xx = bx0 - 1 + c;
                float v = 0.f;
                if (yok && xx >= 0 && xx < W) v = rowp[xx];
                st[r * SB + c] = v;
            }
        }
    }
    __syncthreads();

    float bmax = 0.f;
    int y = by0 + ty;
    int r = ty + 1;
    float gm4[4], xr4[4], yr4[4];
#pragma unroll
    for (int k = 0; k < 4; ++k) {
        int c = tx + 32 * k + 1;
        float a00 = st[(r - 1) * SB + c - 1], a01 = st[(r - 1) * SB + c], a02 = st[(r - 1) * SB + c + 1];
        float a10 = st[r * SB + c - 1], a12 = st[r * SB + c + 1];
        float a20 = st[(r + 1) * SB + c - 1], a21 = st[(r + 1) * SB + c], a22 = st[(r + 1) * SB + c + 1];

        float gx = (a02 - a00) + 2.f * (a12 - a10) + (a22 - a20);
        float gy = (a20 - a00) + 2.f * (a21 - a01) + (a22 - a02);

        gx = fmaxf(gx, 1e-12f);
        gy = fmaxf(gy, 1e-12f);
        float d = gx * gx + gy * gy;
        float rq = __builtin_amdgcn_rsqf(d);
        float gm = d * rq;
        float xv = gx * rq, yv = gy * rq;
        const float ct = -4.37113883e-08f;  // cosf(fp32 pi/2); sin = 1.0 exactly
        gm4[k] = gm;
        xr4[k] = xv * ct - yv;
        yr4[k] = yv * ct + xv;
        bmax = fmaxf(bmax, gm);
    }
#pragma unroll
    for (int k = 0; k < 4; ++k) {
        int idx = y * W + bx0 + tx + 32 * k;
        float* gc = g + (size_t)ch * HW;
        float* xc = xn + (size_t)ch * HW;
        float* yc = yn + (size_t)ch * HW;
        gc[idx] = gm4[k];
        xc[idx] = xr4[k];
        yc[idx] = yr4[k];
    }

    __syncthreads();
    st[tid] = bmax;
    __syncthreads();
    for (int s = 128; s > 0; s >>= 1) {
        if (tid < s) st[tid] = fmaxf(st[tid], st[tid + s]);
        __syncthreads();
    }
    if (tid == 0) gpart[ch * 256 + blockIdx.y * 4 + blockIdx.x] = st[0];
}

// ---------------- shared ETF helpers (LDS stride 136 everywhere) ----------------
#define SWI 136

struct W8 { float w[8]; };

__device__ __forceinline__ W8 ld8(const float* p) {
    W8 o;
    const float4* q = (const float4*)p;
    float4 a = q[0], b = q[1];
    o.w[0] = a.x; o.w[1] = a.y; o.w[2] = a.z; o.w[3] = a.w;
    o.w[4] = b.x; o.w[5] = b.y; o.w[6] = b.z; o.w[7] = b.w;
    return o;
}

// aligned 3xb128; returns floats [2,10) of the 12
__device__ __forceinline__ W8 ld12w(const float* p) {
    W8 o;
    const float4* q = (const float4*)p;
    float4 a = q[0], b = q[1], c = q[2];
    o.w[0] = a.z; o.w[1] = a.w; o.w[2] = b.x; o.w[3] = b.y;
    o.w[4] = b.z; o.w[5] = b.w; o.w[6] = c.x; o.w[7] = c.y;
    return o;
}

__device__ __forceinline__ void contrib8(const W8& gw, const W8& xw, const W8& yw, const W8& ew,
                                         const float* cx, const float* cy, const float* ec,
                                         float* xr, float* yr) {
#pragma unroll
    for (int k = 0; k < 4; ++k) {
#pragma unroll
        for (int d = 0; d < 5; ++d) {
            int n = k + d;
            float dot = cx[k] * xw.w[n] + cy[k] * yw.w[n];
            float wm = __builtin_amdgcn_rcpf(1.f + ew.w[n] * ec[k]);
            float m = gw.w[n] * (wm * dot);
            xr[k] = fmaf(m, xw.w[n], xr[k]);
            yr[k] = fmaf(m, yw.w[n], yr[k]);
        }
    }
}

// 4-px group; WIDE=0: window [base, base+8); WIDE=1: window [base+2, base+10)
// (12-float aligned read). Centers at window idx 2..5.
template <int WIDE>
__device__ __forceinline__ void etf_group(const float* sg, const float* se,
                                          const float* sx, const float* sy,
                                          int base, float* xr, float* yr) {
    W8 cxw = WIDE ? ld12w(sx + base) : ld8(sx + base);
    W8 cyw = WIDE ? ld12w(sy + base) : ld8(sy + base);
    W8 cew = WIDE ? ld12w(se + base) : ld8(se + base);
    float cx[4], cy[4], ec[4];
#pragma unroll
    for (int k = 0; k < 4; ++k) {
        cx[k] = cxw.w[k + 2];
        cy[k] = cyw.w[k + 2];
        ec[k] = __builtin_amdgcn_rcpf(cew.w[k + 2]);  // e^{+2 g_c/gmax}
    }
#pragma unroll
    for (int k = 0; k < 4; ++k) { xr[k] = 0.f; yr[k] = 0.f; }
#pragma unroll
    for (int dy = -2; dy <= 2; ++dy) {
        int rb = base + dy * SWI;
        W8 gw = WIDE ? ld12w(sg + rb) : ld8(sg + rb);
        W8 xw = WIDE ? ld12w(sx + rb) : ld8(sx + rb);
        W8 yw = WIDE ? ld12w(sy + rb) : ld8(sy + rb);
        W8 ew = WIDE ? ld12w(se + rb) : ld8(se + rb);
        contrib8(gw, xw, yw, ew, cx, cy, ec, xr, yr);
    }
}

// per-wave redundant gmax reduction (4 L2-hot loads + butterfly; no barrier)
__device__ __forceinline__ float wave_gmax_s2(const float* gpart, int ch, int lane) {
    const float* gp = gpart + ch * 256;
    float m = fmaxf(fmaxf(gp[lane], gp[lane + 64]), fmaxf(gp[lane + 128], gp[lane + 192]));
#pragma unroll
    for (int k = 32; k > 0; k >>= 1) m = fmaxf(m, __shfl_xor(m, k, 64));
    return -2.f * __builtin_amdgcn_rcpf(m);  // sigmoid(2d/gmax) = 0.5(1+tanh(d/gmax))
}

// ---------------- K2: fused ETF iterations 1+2 (halo-4 staging, 136x16) ----------------
// Phase A computes iter1 on the 132x12 halo-2 region (reflect-virtual coords are exact:
// reflection maps a 5x5 neighborhood to the same value multiset); phase B computes iter2
// for the 128x8 output tile from the updated sx/sy.
__global__ __launch_bounds__(256) void k_iterA(const float* __restrict__ g,
                                               const float* __restrict__ xin,
                                               const float* __restrict__ yin,
                                               const float* __restrict__ gpart,
                                               float* __restrict__ xout,
                                               float* __restrict__ yout) {
    __shared__ __align__(16) float sg[16 * SWI];
    __shared__ __align__(16) float se[16 * SWI];
    __shared__ __align__(16) float sx[16 * SWI];
    __shared__ __align__(16) float sy[16 * SWI];

    int ch = blockIdx.z;
    int bx0 = blockIdx.x * 128, by0 = blockIdx.y * 8;
    int tx = threadIdx.x, ty = threadIdx.y;
    int tid = ty * 32 + tx;
    const size_t cbase = (size_t)ch * HW;

    float s2 = wave_gmax_s2(gpart, ch, tid & 63);

    // stage rows [by0-4, by0+12), cols [bx0-4, bx0+132) with reflect
    const float* gc = g + cbase;
    const float* xc = xin + cbase;
    const float* yc = yin + cbase;
#pragma unroll
    for (int jr = 0; jr < 2; ++jr) {
        int r = ty + 8 * jr;
        {
            int yy = reflect_idx(by0 - 4 + r, H);
            const float* grow = gc + yy * W;
            const float* xrow = xc + yy * W;
            const float* yrow = yc + yy * W;
#pragma unroll
            for (int m = 0; m < 5; ++m) {
                int c = (m < 4) ? (tx + 32 * m) : (128 + tx);
                if (m < 4 || tx < 8) {
                    int xx = reflect_idx(bx0 - 4 + c, W);
                    int s = r * SWI + c;
                    float gv = grow[xx];
                    sg[s] = gv;
                    se[s] = __expf(s2 * gv);
                    sx[s] = xrow[xx];
                    sy[s] = yrow[xx];
                }
            }
        }
    }
    __syncthreads();

    // ---- phase A (iter1): centers rows [2,14) x cols [2,134); 12 x 33 groups = 396
    float oax[2][4], oay[2][4];
#pragma unroll
    for (int rnd = 0; rnd < 2; ++rnd) {
        int gi = tid + rnd * 256;
        if (rnd == 0 || gi < 396) {
            int gr = gi / 33, gm = gi - gr * 33;
            int base = (2 + gr) * SWI + 4 * gm;  // window [4gm,4gm+8), centers 4gm+2..5
            float xr[4], yr[4];
            etf_group<0>(sg, se, sx, sy, base, xr, yr);
#pragma unroll
            for (int k = 0; k < 4; ++k) {
                float iv = __builtin_amdgcn_rsqf(xr[k] * xr[k] + yr[k] * yr[k]);
                oax[rnd][k] = xr[k] * iv;
                oay[rnd][k] = yr[k] * iv;
            }
        }
    }
    __syncthreads();
#pragma unroll
    for (int rnd = 0; rnd < 2; ++rnd) {
        int gi = tid + rnd * 256;
        if (rnd == 0 || gi < 396) {
            int gr = gi / 33, gm = gi - gr * 33;
            int c0 = (2 + gr) * SWI + 2 + 4 * gm;
            *(float2*)&sx[c0] = make_float2(oax[rnd][0], oax[rnd][1]);
            *(float2*)&sx[c0 + 2] = make_float2(oax[rnd][2], oax[rnd][3]);
            *(float2*)&sy[c0] = make_float2(oay[rnd][0], oay[rnd][1]);
            *(float2*)&sy[c0 + 2] = make_float2(oay[rnd][2], oay[rnd][3]);
        }
    }
    __syncthreads();

    // ---- phase B (iter2): centers rows [4,12) x cols [4,132); one 4-px group/thread
    {
        int gm = tid & 31, gr = tid >> 5;
        int base = (4 + gr) * SWI + 4 * gm;  // 12-float read, window [4gm+2, 4gm+10)
        float xr[4], yr[4];
        etf_group<1>(sg, se, sx, sy, base, xr, yr);

        float ox[4], oy[4];
#pragma unroll
        for (int k = 0; k < 4; ++k) {
            float iv = __builtin_amdgcn_rsqf(xr[k] * xr[k] + yr[k] * yr[k]);
            ox[k] = xr[k] * iv;
            oy[k] = yr[k] * iv;
        }
        size_t obase = cbase + (size_t)(by0 + gr) * W + bx0 + 4 * gm;
        *(float4*)(xout + obase) = make_float4(ox[0], ox[1], ox[2], ox[3]);
        *(float4*)(yout + obase) = make_float4(oy[0], oy[1], oy[2], oy[3]);
    }
}

// ---------------- K3: ETF iteration 3 + angle + instance-norm partials ----------------
__global__ __launch_bounds__(256) void k_iterB(const float* __restrict__ g,
                                               const float* __restrict__ xin,
                                               const float* __restrict__ yin,
                                               const float* __restrict__ gpart,
                                               float* __restrict__ out,
                                               double* __restrict__ partials) {
    __shared__ __align__(16) float sg[12 * SWI];
    __shared__ __align__(16) float se[12 * SWI];
    __shared__ __align__(16) float sx[12 * SWI];
    __shared__ __align__(16) float sy[12 * SWI];
    __shared__ double swr[8];

    int ch = blockIdx.z;
    int bx0 = blockIdx.x * 128, by0 = blockIdx.y * 8;
    int tx = threadIdx.x, ty = threadIdx.y;
    int tid = ty * 32 + tx;
    const size_t cbase = (size_t)ch * HW;

    float s2 = wave_gmax_s2(gpart, ch, tid & 63);

    // stage rows [by0-2, by0+10), cols [bx0-2, bx0+130) with reflect
    const float* gc = g + cbase;
    const float* xc = xin + cbase;
    const float* yc = yin + cbase;
#pragma unroll
    for (int jr = 0; jr < 2; ++jr) {
        int r = ty + 8 * jr;
        if (jr == 0 || ty < 4) {
            int yy = reflect_idx(by0 - 2 + r, H);
            const float* grow = gc + yy * W;
            const float* xrow = xc + yy * W;
            const float* yrow = yc + yy * W;
#pragma unroll
            for (int m = 0; m < 5; ++m) {
                int c = (m < 4) ? (tx + 32 * m) : (128 + tx);
                if (m < 4 || tx < 4) {
                    int xx = reflect_idx(bx0 - 2 + c, W);
                    int s = r * SWI + c;
                    float gv = grow[xx];
                    sg[s] = gv;
                    se[s] = __expf(s2 * gv);
                    sx[s] = xrow[xx];
                    sy[s] = yrow[xx];
                }
            }
        }
    }
    __syncthreads();

    // centers: rows [2,10) x cols [2,130); thread -> row ty+2, group base 4*tx
    float a[4];
    double s = 0.0, q = 0.0;
    {
        int base = (ty + 2) * SWI + 4 * tx;  // window [4tx,4tx+8), centers 4tx+2..5
        float xr[4], yr[4];
        etf_group<0>(sg, se, sx, sy, base, xr, yr);
#pragma unroll
        for (int k = 0; k < 4; ++k) {
            float ang = atanf(-yr[k] / xr[k]);  // normalization cancels in the ratio
            a[k] = (180.f * ang) / 3.14159274f;
            s += (double)a[k];
            q += (double)a[k] * (double)a[k];
        }
        size_t obase = cbase + (size_t)(by0 + ty) * W + bx0 + 4 * tx;
        *(float4*)(out + obase) = make_float4(a[0], a[1], a[2], a[3]);
    }

    // wave shuffle-reduce, then 4 leaders through LDS
#pragma unroll
    for (int off = 32; off > 0; off >>= 1) {
        s += __shfl_down(s, off, 64);
        q += __shfl_down(q, off, 64);
    }
    if ((tid & 63) == 0) {
        swr[tid >> 6] = s;
        swr[4 + (tid >> 6)] = q;
    }
    __syncthreads();
    if (tid == 0) {
        double ts = swr[0] + swr[1] + swr[2] + swr[3];
        double tq = swr[4] + swr[5] + swr[6] + swr[7];
        int blk = blockIdx.y * 4 + blockIdx.x;  // 256 blocks per channel
        partials[((size_t)ch * 256 + blk) * 2 + 0] = ts;
        partials[((size_t)ch * 256 + blk) * 2 + 1] = tq;
    }
}

// ---------------- K4: instance norm (inline stats reduce, then normalize) ----------------
__global__ __launch_bounds__(256) void k_norm(float* __restrict__ a,
                                              const double* __restrict__ partials) {
    int ch = blockIdx.y;
    int t = threadIdx.x;

    __shared__ double rs[256], rq[256];
    rs[t] = partials[((size_t)ch * 256 + t) * 2 + 0];
    rq[t] = partials[((size_t)ch * 256 + t) * 2 + 1];
    __syncthreads();
    for (int st = 128; st > 0; st >>= 1) {
        if (t < st) {
            rs[t] += rs[t + st];
            rq[t] += rq[t + st];
        }
        __syncthreads();
    }
    __shared__ float sm, ss;
    if (t == 0) {
        double mean = rs[0] / (double)HW;
        double var = rq[0] / (double)HW - mean * mean;
        sm = (float)mean;
        ss = (float)(1.0 / sqrt(var + 1e-5));
    }
    __syncthreads();
    float mean = sm, sc = ss;

    float4* a4 = (float4*)(a + (size_t)ch * HW + (size_t)blockIdx.x * 4096);
#pragma unroll
    for (int k = 0; k < 4; ++k) {
        float4 v = a4[k * 256 + t];
        v.x = (v.x - mean) * sc;
        v.y = (v.y - mean) * sc;
        v.z = (v.z - mean) * sc;
        v.w = (v.w - mean) * sc;
        a4[k * 256 + t] = v;
    }
}

extern "C" void kernel_launch(void* const* d_in, const int* in_sizes, int n_in,
                              void* d_out, int out_size, void* d_ws, size_t ws_size,
                              hipStream_t stream) {
    (void)in_sizes; (void)n_in; (void)out_size; (void)ws_size;
    const float* img = (const float*)d_in[0];
    float* out = (float*)d_out;

    float* wsf = (float*)d_ws;
    float* gpart = wsf + 512;                       // 6*256
    double* partials = (double*)(wsf + 8192);       // 6*256*2 doubles
    float* g = wsf + 32768;                         // 5 fields of 6 MiB
    float* xnA = g + (size_t)NCH * HW;
    float* ynA = xnA + (size_t)NCH * HW;
    float* xnB = ynA + (size_t)NCH * HW;
    float* ynB = xnB + (size_t)NCH * HW;

    dim3 tile_grid(4, 64, NCH), tile_blk(32, 8);

    k_sobel<<<tile_grid, tile_blk, 0, stream>>>(img, gpart, g, xnA, ynA);
    k_iterA<<<tile_grid, tile_blk, 0, stream>>>(g, xnA, ynA, gpart, xnB, ynB);
    k_iterB<<<tile_grid, tile_blk, 0, stream>>>(g, xnB, ynB, gpart, out, partials);
    k_norm<<<dim3(64, NCH), dim3(256), 0, stream>>>(out, partials);
}

// Round 11
// 123.586 us; speedup vs baseline: 1.2061x; 1.2061x over previous
//
#include <hip/hip_runtime.h>
#include <math.h>

#define H 512
#define W 512
#define HW (H * W)
#define NCH 6

__device__ __forceinline__ int reflect_idx(int p, int n) {
    if (p < 0) p = -p;
    if (p >= n) p = 2 * n - 2 - p;
    return p;
}

// ---------------- K1: Sobel (LDS-tiled, 128x8, 4 px/thread interleaved) ----------------
// cmax (per-channel img max) dropped: pipeline is scale-invariant past the clamp;
// cmax only rescales the 1e-12 clamp threshold (~1e-6 effect). Sobel on RAW img.
__global__ __launch_bounds__(256) void k_sobel(const float* __restrict__ img,
                                               float* __restrict__ gpart,
                                               float* __restrict__ g,
                                               float* __restrict__ xn,
                                               float* __restrict__ yn) {
    const int SB = 132;  // stride; 130 cols used, 10 rows
    __shared__ float st[10 * SB];

    int ch = blockIdx.z;
    int bx0 = blockIdx.x * 128, by0 = blockIdx.y * 8;
    int tx = threadIdx.x, ty = threadIdx.y;
    int tid = ty * 32 + tx;
    const float* im = img + (size_t)ch * HW;

    // static staging: rows ty (+8 if ty<2), cols tx+32m (m=0..3) + tail tx<2 -> 128+tx
#pragma unroll
    for (int jr = 0; jr < 2; ++jr) {
        int r = ty + 8 * jr;
        if (jr == 0 || ty < 2) {
            int yy = by0 - 1 + r;
            bool yok = (yy >= 0 && yy < H);
            const float* rowp = im + yy * W;
#pragma unroll
            for (int m = 0; m < 4; ++m) {
                int c = tx + 32 * m;
                int xx = bx0 - 1 + c;
                float v = 0.f;
                if (yok && xx >= 0 && xx < W) v = rowp[xx];
                st[r * SB + c] = v;
            }
            if (tx < 2) {
                int c = 128 + tx;
                int xx = bx0 - 1 + c;
                float v = 0.f;
                if (yok && xx >= 0 && xx < W) v = rowp[xx];
                st[r * SB + c] = v;
            }
        }
    }
    __syncthreads();

    float bmax = 0.f;
    int y = by0 + ty;
    int r = ty + 1;
    float gm4[4], xr4[4], yr4[4];
#pragma unroll
    for (int k = 0; k < 4; ++k) {
        int c = tx + 32 * k + 1;
        float a00 = st[(r - 1) * SB + c - 1], a01 = st[(r - 1) * SB + c], a02 = st[(r - 1) * SB + c + 1];
        float a10 = st[r * SB + c - 1], a12 = st[r * SB + c + 1];
        float a20 = st[(r + 1) * SB + c - 1], a21 = st[(r + 1) * SB + c], a22 = st[(r + 1) * SB + c + 1];

        float gx = (a02 - a00) + 2.f * (a12 - a10) + (a22 - a20);
        float gy = (a20 - a00) + 2.f * (a21 - a01) + (a22 - a02);

        gx = fmaxf(gx, 1e-12f);
        gy = fmaxf(gy, 1e-12f);
        float d = gx * gx + gy * gy;
        float rq = __builtin_amdgcn_rsqf(d);
        float gm = d * rq;
        float xv = gx * rq, yv = gy * rq;
        const float ct = -4.37113883e-08f;  // cosf(fp32 pi/2); sin = 1.0 exactly
        gm4[k] = gm;
        xr4[k] = xv * ct - yv;
        yr4[k] = yv * ct + xv;
        bmax = fmaxf(bmax, gm);
    }
#pragma unroll
    for (int k = 0; k < 4; ++k) {
        int idx = y * W + bx0 + tx + 32 * k;
        float* gc = g + (size_t)ch * HW;
        float* xc = xn + (size_t)ch * HW;
        float* yc = yn + (size_t)ch * HW;
        gc[idx] = gm4[k];
        xc[idx] = xr4[k];
        yc[idx] = yr4[k];
    }

    __syncthreads();
    st[tid] = bmax;
    __syncthreads();
    for (int s = 128; s > 0; s >>= 1) {
        if (tid < s) st[tid] = fmaxf(st[tid], st[tid + s]);
        __syncthreads();
    }
    if (tid == 0) gpart[ch * 256 + blockIdx.y * 4 + blockIdx.x] = st[0];
}

struct W8 { float w[8]; };

// per-wave redundant gmax reduction (4 L2-hot loads + butterfly; no barrier) -> s2
// [proven in R10's k_iterA/k_iterB]
__device__ __forceinline__ float wave_gmax_s2(const float* gpart, int ch, int lane) {
    const float* gp = gpart + ch * 256;
    float m = fmaxf(fmaxf(gp[lane], gp[lane + 64]), fmaxf(gp[lane + 128], gp[lane + 192]));
#pragma unroll
    for (int k = 32; k > 0; k >>= 1) m = fmaxf(m, __shfl_xor(m, k, 64));
    return -2.f * __builtin_amdgcn_rcpf(m);  // sigmoid(2d/gmax) = 0.5(1+tanh(d/gmax))
}

// ---------------- K2: one ETF iteration, 4 px/thread (LAST fuses angle+partials) -------
template <bool LAST>
__global__ __launch_bounds__(256) void k_iter(const float* __restrict__ g,
                                              const float* __restrict__ xin,
                                              const float* __restrict__ yin,
                                              const float* __restrict__ gpart,
                                              float* __restrict__ xout,
                                              float* __restrict__ yout,
                                              double* __restrict__ partials) {
    const int SW = 136;  // stride; tile 128x8 + halo 2 -> 132 cols used, 12 rows
    __shared__ __align__(16) float sg[12 * SW];
    __shared__ __align__(16) float se[12 * SW];
    __shared__ __align__(16) float sx[12 * SW];
    __shared__ __align__(16) float sy[12 * SW];
    __shared__ double swr[8];

    int ch = blockIdx.z;
    int bx0 = blockIdx.x * 128, by0 = blockIdx.y * 8;
    int tx = threadIdx.x, ty = threadIdx.y;
    int tid = ty * 32 + tx;
    const size_t cbase = (size_t)ch * HW;

    float s2 = wave_gmax_s2(gpart, ch, tid & 63);

    // static staging: rows ty (+8 if ty<4), cols tx+32m (m=0..3) + tail tx<4 -> 128+tx
    const float* gc = g + cbase;
    const float* xc = xin + cbase;
    const float* yc = yin + cbase;
#pragma unroll
    for (int jr = 0; jr < 2; ++jr) {
        int r = ty + 8 * jr;
        if (jr == 0 || ty < 4) {
            int yy = reflect_idx(by0 - 2 + r, H);
            const float* grow = gc + yy * W;
            const float* xrow = xc + yy * W;
            const float* yrow = yc + yy * W;
#pragma unroll
            for (int m = 0; m < 5; ++m) {
                int c = (m < 4) ? (tx + 32 * m) : (128 + tx);
                if (m < 4 || tx < 4) {
                    int xx = reflect_idx(bx0 - 2 + c, W);
                    int s = r * SW + c;
                    float gv = grow[xx];
                    sg[s] = gv;
                    se[s] = __expf(s2 * gv);
                    sx[s] = xrow[xx];
                    sy[s] = yrow[xx];
                }
            }
        }
    }
    __syncthreads();

    // thread handles pixels x = bx0 + 4*tx + k, k=0..3; LDS center col = 4*tx+2+k
    auto LD8 = [&](const float* s, int r) {
        W8 o;
        const float4* p = (const float4*)(s + r * SW + 4 * tx);
        float4 a = p[0], b = p[1];
        o.w[0] = a.x; o.w[1] = a.y; o.w[2] = a.z; o.w[3] = a.w;
        o.w[4] = b.x; o.w[5] = b.y; o.w[6] = b.z; o.w[7] = b.w;
        return o;
    };

    int row0 = ty + 2;
    W8 cxw = LD8(sx, row0), cyw = LD8(sy, row0), cew = LD8(se, row0);
    float cx[4], cy[4], ec[4];
#pragma unroll
    for (int k = 0; k < 4; ++k) {
        cx[k] = cxw.w[k + 2];
        cy[k] = cyw.w[k + 2];
        ec[k] = __builtin_amdgcn_rcpf(cew.w[k + 2]);  // e^{+2 g_c/gmax}
    }

    float xr[4] = {0.f, 0.f, 0.f, 0.f}, yr[4] = {0.f, 0.f, 0.f, 0.f};
#pragma unroll
    for (int dy = -2; dy <= 2; ++dy) {
        W8 gw = LD8(sg, row0 + dy), xw = LD8(sx, row0 + dy),
           yw = LD8(sy, row0 + dy), ew = LD8(se, row0 + dy);
#pragma unroll
        for (int k = 0; k < 4; ++k) {
#pragma unroll
            for (int dxi = 0; dxi < 5; ++dxi) {
                int n = k + dxi;
                float dot = cx[k] * xw.w[n] + cy[k] * yw.w[n];
                float wm = __builtin_amdgcn_rcpf(1.f + ew.w[n] * ec[k]);
                float m = gw.w[n] * (wm * dot);
                xr[k] = fmaf(m, xw.w[n], xr[k]);
                yr[k] = fmaf(m, yw.w[n], yr[k]);
            }
        }
    }

    size_t obase = cbase + (size_t)(by0 + ty) * W + bx0 + 4 * tx;
    if (!LAST) {
        float ox[4], oy[4];
#pragma unroll
        for (int k = 0; k < 4; ++k) {
            float im2 = __builtin_amdgcn_rsqf(xr[k] * xr[k] + yr[k] * yr[k]);
            ox[k] = xr[k] * im2;
            oy[k] = yr[k] * im2;
        }
        *(float4*)(xout + obase) = make_float4(ox[0], ox[1], ox[2], ox[3]);
        *(float4*)(yout + obase) = make_float4(oy[0], oy[1], oy[2], oy[3]);
    } else {
        // normalization cancels in the ratio: angle = atan(-yr/xr)
        float a[4];
        double s = 0.0, q = 0.0;
#pragma unroll
        for (int k = 0; k < 4; ++k) {
            float ang = atanf(-yr[k] / xr[k]);
            a[k] = (180.f * ang) / 3.14159274f;
            s += (double)a[k];
            q += (double)a[k] * (double)a[k];
        }
        *(float4*)(xout + obase) = make_float4(a[0], a[1], a[2], a[3]);

        // wave shuffle-reduce, then 4 leaders through LDS
#pragma unroll
        for (int off = 32; off > 0; off >>= 1) {
            s += __shfl_down(s, off, 64);
            q += __shfl_down(q, off, 64);
        }
        if ((tid & 63) == 0) {
            swr[tid >> 6] = s;
            swr[4 + (tid >> 6)] = q;
        }
        __syncthreads();
        if (tid == 0) {
            double ts = swr[0] + swr[1] + swr[2] + swr[3];
            double tq = swr[4] + swr[5] + swr[6] + swr[7];
            int blk = blockIdx.y * 4 + blockIdx.x;  // 256 blocks per channel
            partials[((size_t)ch * 256 + blk) * 2 + 0] = ts;
            partials[((size_t)ch * 256 + blk) * 2 + 1] = tq;
        }
    }
}

// ---------------- K3: instance norm (inline stats reduce, then normalize) ----------------
__global__ __launch_bounds__(256) void k_norm(float* __restrict__ a,
                                              const double* __restrict__ partials) {
    int ch = blockIdx.y;
    int t = threadIdx.x;

    __shared__ double rs[256], rq[256];
    rs[t] = partials[((size_t)ch * 256 + t) * 2 + 0];
    rq[t] = partials[((size_t)ch * 256 + t) * 2 + 1];
    __syncthreads();
    for (int st = 128; st > 0; st >>= 1) {
        if (t < st) {
            rs[t] += rs[t + st];
            rq[t] += rq[t + st];
        }
        __syncthreads();
    }
    __shared__ float sm, ss;
    if (t == 0) {
        double mean = rs[0] / (double)HW;
        double var = rq[0] / (double)HW - mean * mean;
        sm = (float)mean;
        ss = (float)(1.0 / sqrt(var + 1e-5));
    }
    __syncthreads();
    float mean = sm, sc = ss;

    float4* a4 = (float4*)(a + (size_t)ch * HW + (size_t)blockIdx.x * 4096);
#pragma unroll
    for (int k = 0; k < 4; ++k) {
        float4 v = a4[k * 256 + t];
        v.x = (v.x - mean) * sc;
        v.y = (v.y - mean) * sc;
        v.z = (v.z - mean) * sc;
        v.w = (v.w - mean) * sc;
        a4[k * 256 + t] = v;
    }
}

extern "C" void kernel_launch(void* const* d_in, const int* in_sizes, int n_in,
                              void* d_out, int out_size, void* d_ws, size_t ws_size,
                              hipStream_t stream) {
    (void)in_sizes; (void)n_in; (void)out_size; (void)ws_size;
    const float* img = (const float*)d_in[0];
    float* out = (float*)d_out;

    float* wsf = (float*)d_ws;
    float* gpart = wsf + 512;                       // 6*256
    double* partials = (double*)(wsf + 8192);       // 6*256*2 doubles
    float* g = wsf + 32768;                         // 5 fields of 6 MiB
    float* xnA = g + (size_t)NCH * HW;
    float* ynA = xnA + (size_t)NCH * HW;
    float* xnB = ynA + (size_t)NCH * HW;
    float* ynB = xnB + (size_t)NCH * HW;

    dim3 tile_grid(4, 64, NCH), tile_blk(32, 8);

    k_sobel<<<tile_grid, tile_blk, 0, stream>>>(img, gpart, g, xnA, ynA);
    k_iter<false><<<tile_grid, tile_blk, 0, stream>>>(g, xnA, ynA, gpart, xnB, ynB, nullptr);
    k_iter<false><<<tile_grid, tile_blk, 0, stream>>>(g, xnB, ynB, gpart, xnA, ynA, nullptr);
    k_iter<true><<<tile_grid, tile_blk, 0, stream>>>(g, xnA, ynA, gpart, out, nullptr, partials);
    k_norm<<<dim3(64, NCH), dim3(256), 0, stream>>>(out, partials);
}

// Round 12
// 121.031 us; speedup vs baseline: 1.2316x; 1.0211x over previous
//
#include <hip/hip_runtime.h>
#include <hip/hip_fp16.h>
#include <math.h>

#define H 512
#define W 512
#define HW (H * W)
#define NCH 6

__device__ __forceinline__ int reflect_idx(int p, int n) {
    if (p < 0) p = -p;
    if (p >= n) p = 2 * n - 2 - p;
    return p;
}

// ---------------- K1: Sobel (LDS-tiled, 128x8, 4 px/thread interleaved) ----------------
// cmax (per-channel img max) dropped: pipeline is scale-invariant past the clamp;
// cmax only rescales the 1e-12 clamp threshold (~1e-6 effect). Sobel on RAW img.
// Outputs: gh (fp16 gradient mag), xy (packed half2 rotated tangent), fp32 gpart maxima.
__global__ __launch_bounds__(256) void k_sobel(const float* __restrict__ img,
                                               float* __restrict__ gpart,
                                               __half* __restrict__ gh,
                                               __half2* __restrict__ xy) {
    const int SB = 132;  // stride; 130 cols used, 10 rows
    __shared__ float st[10 * SB];

    int ch = blockIdx.z;
    int bx0 = blockIdx.x * 128, by0 = blockIdx.y * 8;
    int tx = threadIdx.x, ty = threadIdx.y;
    int tid = ty * 32 + tx;
    const float* im = img + (size_t)ch * HW;

    // static staging: rows ty (+8 if ty<2), cols tx+32m (m=0..3) + tail tx<2 -> 128+tx
#pragma unroll
    for (int jr = 0; jr < 2; ++jr) {
        int r = ty + 8 * jr;
        if (jr == 0 || ty < 2) {
            int yy = by0 - 1 + r;
            bool yok = (yy >= 0 && yy < H);
            const float* rowp = im + yy * W;
#pragma unroll
            for (int m = 0; m < 4; ++m) {
                int c = tx + 32 * m;
                int xx = bx0 - 1 + c;
                float v = 0.f;
                if (yok && xx >= 0 && xx < W) v = rowp[xx];
                st[r * SB + c] = v;
            }
            if (tx < 2) {
                int c = 128 + tx;
                int xx = bx0 - 1 + c;
                float v = 0.f;
                if (yok && xx >= 0 && xx < W) v = rowp[xx];
                st[r * SB + c] = v;
            }
        }
    }
    __syncthreads();

    float bmax = 0.f;
    int y = by0 + ty;
    int r = ty + 1;
    float gm4[4], xr4[4], yr4[4];
#pragma unroll
    for (int k = 0; k < 4; ++k) {
        int c = tx + 32 * k + 1;
        float a00 = st[(r - 1) * SB + c - 1], a01 = st[(r - 1) * SB + c], a02 = st[(r - 1) * SB + c + 1];
        float a10 = st[r * SB + c - 1], a12 = st[r * SB + c + 1];
        float a20 = st[(r + 1) * SB + c - 1], a21 = st[(r + 1) * SB + c], a22 = st[(r + 1) * SB + c + 1];

        float gx = (a02 - a00) + 2.f * (a12 - a10) + (a22 - a20);
        float gy = (a20 - a00) + 2.f * (a21 - a01) + (a22 - a02);

        gx = fmaxf(gx, 1e-12f);
        gy = fmaxf(gy, 1e-12f);
        float d = gx * gx + gy * gy;
        float rq = __builtin_amdgcn_rsqf(d);
        float gm = d * rq;
        float xv = gx * rq, yv = gy * rq;
        const float ct = -4.37113883e-08f;  // cosf(fp32 pi/2); sin = 1.0 exactly
        gm4[k] = gm;
        xr4[k] = xv * ct - yv;
        yr4[k] = yv * ct + xv;
        bmax = fmaxf(bmax, gm);
    }
#pragma unroll
    for (int k = 0; k < 4; ++k) {
        int idx = y * W + bx0 + tx + 32 * k;
        __half* gc = gh + (size_t)ch * HW;
        __half2* xc = xy + (size_t)ch * HW;
        gc[idx] = __float2half(gm4[k]);
        xc[idx] = __floats2half2_rn(xr4[k], yr4[k]);
    }

    __syncthreads();
    st[tid] = bmax;
    __syncthreads();
    for (int s = 128; s > 0; s >>= 1) {
        if (tid < s) st[tid] = fmaxf(st[tid], st[tid + s]);
        __syncthreads();
    }
    if (tid == 0) gpart[ch * 256 + blockIdx.y * 4 + blockIdx.x] = st[0];
}

struct W8 { float w[8]; };

// per-wave redundant gmax reduction (4 L2-hot loads + butterfly; no barrier) -> s2
__device__ __forceinline__ float wave_gmax_s2(const float* gpart, int ch, int lane) {
    const float* gp = gpart + ch * 256;
    float m = fmaxf(fmaxf(gp[lane], gp[lane + 64]), fmaxf(gp[lane + 128], gp[lane + 192]));
#pragma unroll
    for (int k = 32; k > 0; k >>= 1) m = fmaxf(m, __shfl_xor(m, k, 64));
    return -2.f * __builtin_amdgcn_rcpf(m);  // sigmoid(2d/gmax) = 0.5(1+tanh(d/gmax))
}

// ---------------- K2: one ETF iteration, 4 px/thread (LAST fuses angle+partials) -------
// fp16 global fields; LDS and all arithmetic fp32 (convert once at staging).
template <bool LAST>
__global__ __launch_bounds__(256) void k_iter(const __half* __restrict__ gh,
                                              const __half2* __restrict__ xyin,
                                              const float* __restrict__ gpart,
                                              __half2* __restrict__ xyout,
                                              float* __restrict__ aout,
                                              double* __restrict__ partials) {
    const int SW = 136;  // stride; tile 128x8 + halo 2 -> 132 cols used, 12 rows
    __shared__ __align__(16) float sg[12 * SW];
    __shared__ __align__(16) float se[12 * SW];
    __shared__ __align__(16) float sx[12 * SW];
    __shared__ __align__(16) float sy[12 * SW];
    __shared__ double swr[8];

    int ch = blockIdx.z;
    int bx0 = blockIdx.x * 128, by0 = blockIdx.y * 8;
    int tx = threadIdx.x, ty = threadIdx.y;
    int tid = ty * 32 + tx;
    const size_t cbase = (size_t)ch * HW;

    float s2 = wave_gmax_s2(gpart, ch, tid & 63);

    // static staging: rows ty (+8 if ty<4), cols tx+32m (m=0..3) + tail tx<4 -> 128+tx
    const __half* gc = gh + cbase;
    const __half2* xc = xyin + cbase;
#pragma unroll
    for (int jr = 0; jr < 2; ++jr) {
        int r = ty + 8 * jr;
        if (jr == 0 || ty < 4) {
            int yy = reflect_idx(by0 - 2 + r, H);
            const __half* grow = gc + yy * W;
            const __half2* xrow = xc + yy * W;
#pragma unroll
            for (int m = 0; m < 5; ++m) {
                int c = (m < 4) ? (tx + 32 * m) : (128 + tx);
                if (m < 4 || tx < 4) {
                    int xx = reflect_idx(bx0 - 2 + c, W);
                    int s = r * SW + c;
                    float gv = __half2float(grow[xx]);
                    float2 v = __half22float2(xrow[xx]);
                    sg[s] = gv;
                    se[s] = __expf(s2 * gv);
                    sx[s] = v.x;
                    sy[s] = v.y;
                }
            }
        }
    }
    __syncthreads();

    // thread handles pixels x = bx0 + 4*tx + k, k=0..3; LDS center col = 4*tx+2+k
    auto LD8 = [&](const float* s, int r) {
        W8 o;
        const float4* p = (const float4*)(s + r * SW + 4 * tx);
        float4 a = p[0], b = p[1];
        o.w[0] = a.x; o.w[1] = a.y; o.w[2] = a.z; o.w[3] = a.w;
        o.w[4] = b.x; o.w[5] = b.y; o.w[6] = b.z; o.w[7] = b.w;
        return o;
    };

    int row0 = ty + 2;
    W8 cxw = LD8(sx, row0), cyw = LD8(sy, row0), cew = LD8(se, row0);
    float cx[4], cy[4], ec[4];
#pragma unroll
    for (int k = 0; k < 4; ++k) {
        cx[k] = cxw.w[k + 2];
        cy[k] = cyw.w[k + 2];
        ec[k] = __builtin_amdgcn_rcpf(cew.w[k + 2]);  // e^{+2 g_c/gmax}
    }

    float xr[4] = {0.f, 0.f, 0.f, 0.f}, yr[4] = {0.f, 0.f, 0.f, 0.f};
#pragma unroll
    for (int dy = -2; dy <= 2; ++dy) {
        W8 gw = LD8(sg, row0 + dy), xw = LD8(sx, row0 + dy),
           yw = LD8(sy, row0 + dy), ew = LD8(se, row0 + dy);
#pragma unroll
        for (int k = 0; k < 4; ++k) {
#pragma unroll
            for (int dxi = 0; dxi < 5; ++dxi) {
                int n = k + dxi;
                float dot = cx[k] * xw.w[n] + cy[k] * yw.w[n];
                float wm = __builtin_amdgcn_rcpf(1.f + ew.w[n] * ec[k]);
                float m = gw.w[n] * (wm * dot);
                xr[k] = fmaf(m, xw.w[n], xr[k]);
                yr[k] = fmaf(m, yw.w[n], yr[k]);
            }
        }
    }

    size_t obase = cbase + (size_t)(by0 + ty) * W + bx0 + 4 * tx;
    if (!LAST) {
        union { __half2 h[4]; float4 f; } u;
#pragma unroll
        for (int k = 0; k < 4; ++k) {
            float im2 = __builtin_amdgcn_rsqf(xr[k] * xr[k] + yr[k] * yr[k]);
            u.h[k] = __floats2half2_rn(xr[k] * im2, yr[k] * im2);
        }
        *(float4*)(xyout + obase) = u.f;  // 4 px = 16 B, aligned
    } else {
        // normalization cancels in the ratio: angle = atan(-yr/xr)
        float a[4];
        double s = 0.0, q = 0.0;
#pragma unroll
        for (int k = 0; k < 4; ++k) {
            float ang = atanf(-yr[k] / xr[k]);
            a[k] = (180.f * ang) / 3.14159274f;
            s += (double)a[k];
            q += (double)a[k] * (double)a[k];
        }
        *(float4*)(aout + obase) = make_float4(a[0], a[1], a[2], a[3]);

        // wave shuffle-reduce, then 4 leaders through LDS
#pragma unroll
        for (int off = 32; off > 0; off >>= 1) {
            s += __shfl_down(s, off, 64);
            q += __shfl_down(q, off, 64);
        }
        if ((tid & 63) == 0) {
            swr[tid >> 6] = s;
            swr[4 + (tid >> 6)] = q;
        }
        __syncthreads();
        if (tid == 0) {
            double ts = swr[0] + swr[1] + swr[2] + swr[3];
            double tq = swr[4] + swr[5] + swr[6] + swr[7];
            int blk = blockIdx.y * 4 + blockIdx.x;  // 256 blocks per channel
            partials[((size_t)ch * 256 + blk) * 2 + 0] = ts;
            partials[((size_t)ch * 256 + blk) * 2 + 1] = tq;
        }
    }
}

// ---------------- K3: instance norm (inline stats reduce, then normalize) ----------------
__global__ __launch_bounds__(256) void k_norm(float* __restrict__ a,
                                              const double* __restrict__ partials) {
    int ch = blockIdx.y;
    int t = threadIdx.x;

    __shared__ double rs[256], rq[256];
    rs[t] = partials[((size_t)ch * 256 + t) * 2 + 0];
    rq[t] = partials[((size_t)ch * 256 + t) * 2 + 1];
    __syncthreads();
    for (int st = 128; st > 0; st >>= 1) {
        if (t < st) {
            rs[t] += rs[t + st];
            rq[t] += rq[t + st];
        }
        __syncthreads();
    }
    __shared__ float sm, ss;
    if (t == 0) {
        double mean = rs[0] / (double)HW;
        double var = rq[0] / (double)HW - mean * mean;
        sm = (float)mean;
        ss = (float)(1.0 / sqrt(var + 1e-5));
    }
    __syncthreads();
    float mean = sm, sc = ss;

    float4* a4 = (float4*)(a + (size_t)ch * HW + (size_t)blockIdx.x * 4096);
#pragma unroll
    for (int k = 0; k < 4; ++k) {
        float4 v = a4[k * 256 + t];
        v.x = (v.x - mean) * sc;
        v.y = (v.y - mean) * sc;
        v.z = (v.z - mean) * sc;
        v.w = (v.w - mean) * sc;
        a4[k * 256 + t] = v;
    }
}

extern "C" void kernel_launch(void* const* d_in, const int* in_sizes, int n_in,
                              void* d_out, int out_size, void* d_ws, size_t ws_size,
                              hipStream_t stream) {
    (void)in_sizes; (void)n_in; (void)out_size; (void)ws_size;
    const float* img = (const float*)d_in[0];
    float* out = (float*)d_out;

    char* wsb = (char*)d_ws;
    float* gpart = (float*)(wsb + 2048);            // 6*256 fp32
    double* partials = (double*)(wsb + 32768);      // 6*256*2 doubles = 24 KiB
    __half* gh = (__half*)(wsb + 131072);           // 3 MiB
    __half2* xyA = (__half2*)(wsb + 131072 + 3 * 1024 * 1024);  // 6 MiB
    __half2* xyB = xyA + (size_t)NCH * HW;                      // 6 MiB

    dim3 tile_grid(4, 64, NCH), tile_blk(32, 8);

    k_sobel<<<tile_grid, tile_blk, 0, stream>>>(img, gpart, gh, xyA);
    k_iter<false><<<tile_grid, tile_blk, 0, stream>>>(gh, xyA, gpart, xyB, nullptr, nullptr);
    k_iter<false><<<tile_grid, tile_blk, 0, stream>>>(gh, xyB, gpart, xyA, nullptr, nullptr);
    k_iter<true><<<tile_grid, tile_blk, 0, stream>>>(gh, xyA, gpart, nullptr, out, partials);
    k_norm<<<dim3(64, NCH), dim3(256), 0, stream>>>(out, partials);
}